// Round 1
// baseline (80.160 us; speedup 1.0000x reference)
//
#include <hip/hip_runtime.h>
#include <math.h>

#define NROWS 4096
#define LMAX 256
#define KDIM 256

__global__ __launch_bounds__(256) void epanre_kernel(
    const float* __restrict__ table,
    const float* __restrict__ w1,
    const float* __restrict__ w2,
    const int*   __restrict__ cand_idx,
    const int*   __restrict__ neigh_idx,
    const int*   __restrict__ lengths,
    float*       __restrict__ out)
{
    const int n   = blockIdx.x;
    const int tid = threadIdx.x;

    __shared__ __align__(16) float s_w[LMAX];
    __shared__ int   s_idx[LMAX];
    __shared__ __align__(16) float s_cand[KDIM];
    __shared__ float s_red[4];
    __shared__ float s_bcast;

    const int len = lengths[n];

    // ---- Phase 1: masked logits, candidate row, neighbour indices ----
    float v = -INFINITY;
    if (tid < len) v = w1[(size_t)n * LMAX + tid] + w2[(size_t)n * LMAX + tid];
    s_idx[tid]  = neigh_idx[(size_t)n * LMAX + tid];
    s_cand[tid] = table[(size_t)cand_idx[n] * KDIM + tid];

    // block max (wave shfl reduce, then across the 4 waves via LDS)
    float m = v;
    #pragma unroll
    for (int off = 32; off >= 1; off >>= 1)
        m = fmaxf(m, __shfl_down(m, off, 64));
    if ((tid & 63) == 0) s_red[tid >> 6] = m;
    __syncthreads();
    if (tid == 0)
        s_bcast = fmaxf(fmaxf(s_red[0], s_red[1]), fmaxf(s_red[2], s_red[3]));
    __syncthreads();
    m = s_bcast;

    // block sum of exp
    float e = (tid < len) ? __expf(v - m) : 0.0f;
    float s = e;
    #pragma unroll
    for (int off = 32; off >= 1; off >>= 1)
        s += __shfl_down(s, off, 64);
    if ((tid & 63) == 0) s_red[tid >> 6] = s;
    __syncthreads();
    if (tid == 0) s_bcast = s_red[0] + s_red[1] + s_red[2] + s_red[3];
    __syncthreads();
    const float inv = 1.0f / s_bcast;
    s_w[tid] = e * inv;
    __syncthreads();

    // ---- Phase 2: gather-weighted sum; 4 lane-groups handle 4 l's/iter ----
    const int g    = tid >> 6;   // which of 4 neighbours in this iteration
    const int lane = tid & 63;   // 64 lanes x float4 = 256 floats = one row
    const float4* tab4 = (const float4*)table;
    float4 acc = make_float4(0.f, 0.f, 0.f, 0.f);

    for (int l0 = 0; l0 < len; l0 += 4) {
        const int   l = l0 + g;              // l <= 255 always (l0 <= 252)
        const float w = (l < len) ? s_w[l] : 0.0f;
        const int   idx = s_idx[l];
        const float4 t = tab4[(size_t)idx * (KDIM / 4) + lane];
        acc.x = fmaf(w, t.x, acc.x);
        acc.y = fmaf(w, t.y, acc.y);
        acc.z = fmaf(w, t.z, acc.z);
        acc.w = fmaf(w, t.w, acc.w);
    }

    // ---- Epilogue: dot with candidate fragment, block reduce ----
    const float4 c = ((const float4*)s_cand)[lane];
    float partial = acc.x * c.x + acc.y * c.y + acc.z * c.z + acc.w * c.w;
    #pragma unroll
    for (int off = 32; off >= 1; off >>= 1)
        partial += __shfl_down(partial, off, 64);
    if (lane == 0) s_red[g] = partial;
    __syncthreads();
    if (tid == 0) out[n] = s_red[0] + s_red[1] + s_red[2] + s_red[3];
}

extern "C" void kernel_launch(void* const* d_in, const int* in_sizes, int n_in,
                              void* d_out, int out_size, void* d_ws, size_t ws_size,
                              hipStream_t stream) {
    const float* table     = (const float*)d_in[0];
    const float* w1        = (const float*)d_in[1];
    const float* w2        = (const float*)d_in[2];
    const int*   cand_idx  = (const int*)d_in[3];
    const int*   neigh_idx = (const int*)d_in[4];
    const int*   lengths   = (const int*)d_in[5];
    float* out = (float*)d_out;

    epanre_kernel<<<NROWS, 256, 0, stream>>>(table, w1, w2, cand_idx,
                                             neigh_idx, lengths, out);
}

// Round 2
// 80.108 us; speedup vs baseline: 1.0006x; 1.0006x over previous
//
#include <hip/hip_runtime.h>
#include <math.h>

#define NROWS 4096
#define LMAX 256
#define KDIM 256

__global__ __launch_bounds__(256) void epanre_kernel(
    const float* __restrict__ table,
    const float* __restrict__ w1,
    const float* __restrict__ w2,
    const int*   __restrict__ cand_idx,
    const int*   __restrict__ neigh_idx,
    const int*   __restrict__ lengths,
    float*       __restrict__ out)
{
    const int n   = blockIdx.x;
    const int tid = threadIdx.x;

    __shared__ __align__(16) float s_w[LMAX];
    __shared__ int   s_idx[LMAX];
    __shared__ __align__(16) float s_cand[KDIM];
    __shared__ float s_red[4];
    __shared__ float s_bcast;

    const int len = lengths[n];

    // ---- Phase 1: masked logits, candidate row, neighbour indices ----
    float v = -INFINITY;
    if (tid < len) v = w1[(size_t)n * LMAX + tid] + w2[(size_t)n * LMAX + tid];
    s_idx[tid]  = neigh_idx[(size_t)n * LMAX + tid];
    s_cand[tid] = table[(size_t)cand_idx[n] * KDIM + tid];

    // block max (wave shfl reduce, then across the 4 waves via LDS)
    float m = v;
    #pragma unroll
    for (int off = 32; off >= 1; off >>= 1)
        m = fmaxf(m, __shfl_down(m, off, 64));
    if ((tid & 63) == 0) s_red[tid >> 6] = m;
    __syncthreads();
    if (tid == 0)
        s_bcast = fmaxf(fmaxf(s_red[0], s_red[1]), fmaxf(s_red[2], s_red[3]));
    __syncthreads();
    m = s_bcast;

    // block sum of exp
    float e = (tid < len) ? __expf(v - m) : 0.0f;
    float s = e;
    #pragma unroll
    for (int off = 32; off >= 1; off >>= 1)
        s += __shfl_down(s, off, 64);
    if ((tid & 63) == 0) s_red[tid >> 6] = s;
    __syncthreads();
    if (tid == 0) s_bcast = s_red[0] + s_red[1] + s_red[2] + s_red[3];
    __syncthreads();
    const float inv = 1.0f / s_bcast;
    s_w[tid] = e * inv;   // zero for tid >= len  (e == 0 there)
    __syncthreads();

    // ---- Phase 2: gather-weighted sum; 8 rows in flight per wave ----
    const int g    = tid >> 6;   // wave id: which of 4 l-slots this wave owns
    const int lane = tid & 63;   // 64 lanes x float4 = 256 floats = one row
    const float4* tab4 = (const float4*)table;

    float4 a0 = make_float4(0.f,0.f,0.f,0.f);
    float4 a1 = make_float4(0.f,0.f,0.f,0.f);
    float4 a2 = make_float4(0.f,0.f,0.f,0.f);
    float4 a3 = make_float4(0.f,0.f,0.f,0.f);

    int l0 = 0;
    // main loop: 32 l's per iteration, 8 handled by this wave (stride 4)
    for (; l0 + 32 <= len; l0 += 32) {
        float w[8]; int id[8]; float4 t[8];
        #pragma unroll
        for (int u = 0; u < 8; ++u) {
            const int l = l0 + u * 4 + g;     // < len, s_w zero-padded anyway
            w[u]  = s_w[l];
            id[u] = s_idx[l];
        }
        #pragma unroll
        for (int u = 0; u < 8; ++u)
            t[u] = tab4[(size_t)id[u] * (KDIM / 4) + lane];
        a0.x = fmaf(w[0], t[0].x, a0.x); a0.y = fmaf(w[0], t[0].y, a0.y);
        a0.z = fmaf(w[0], t[0].z, a0.z); a0.w = fmaf(w[0], t[0].w, a0.w);
        a1.x = fmaf(w[1], t[1].x, a1.x); a1.y = fmaf(w[1], t[1].y, a1.y);
        a1.z = fmaf(w[1], t[1].z, a1.z); a1.w = fmaf(w[1], t[1].w, a1.w);
        a2.x = fmaf(w[2], t[2].x, a2.x); a2.y = fmaf(w[2], t[2].y, a2.y);
        a2.z = fmaf(w[2], t[2].z, a2.z); a2.w = fmaf(w[2], t[2].w, a2.w);
        a3.x = fmaf(w[3], t[3].x, a3.x); a3.y = fmaf(w[3], t[3].y, a3.y);
        a3.z = fmaf(w[3], t[3].z, a3.z); a3.w = fmaf(w[3], t[3].w, a3.w);
        a0.x = fmaf(w[4], t[4].x, a0.x); a0.y = fmaf(w[4], t[4].y, a0.y);
        a0.z = fmaf(w[4], t[4].z, a0.z); a0.w = fmaf(w[4], t[4].w, a0.w);
        a1.x = fmaf(w[5], t[5].x, a1.x); a1.y = fmaf(w[5], t[5].y, a1.y);
        a1.z = fmaf(w[5], t[5].z, a1.z); a1.w = fmaf(w[5], t[5].w, a1.w);
        a2.x = fmaf(w[6], t[6].x, a2.x); a2.y = fmaf(w[6], t[6].y, a2.y);
        a2.z = fmaf(w[6], t[6].z, a2.z); a2.w = fmaf(w[6], t[6].w, a2.w);
        a3.x = fmaf(w[7], t[7].x, a3.x); a3.y = fmaf(w[7], t[7].y, a3.y);
        a3.z = fmaf(w[7], t[7].z, a3.z); a3.w = fmaf(w[7], t[7].w, a3.w);
    }
    // tail: up to 31 remaining l's, 4 per iteration (wave-uniform guard)
    for (; l0 < len; l0 += 4) {
        const int l = l0 + g;
        if (l < len) {                         // wave-uniform branch
            const float w   = s_w[l];
            const int   idx = s_idx[l];
            const float4 t  = tab4[(size_t)idx * (KDIM / 4) + lane];
            a0.x = fmaf(w, t.x, a0.x); a0.y = fmaf(w, t.y, a0.y);
            a0.z = fmaf(w, t.z, a0.z); a0.w = fmaf(w, t.w, a0.w);
        }
    }

    float4 acc;
    acc.x = (a0.x + a1.x) + (a2.x + a3.x);
    acc.y = (a0.y + a1.y) + (a2.y + a3.y);
    acc.z = (a0.z + a1.z) + (a2.z + a3.z);
    acc.w = (a0.w + a1.w) + (a2.w + a3.w);

    // ---- Epilogue: dot with candidate fragment, block reduce ----
    const float4 c = ((const float4*)s_cand)[lane];
    float partial = acc.x * c.x + acc.y * c.y + acc.z * c.z + acc.w * c.w;
    #pragma unroll
    for (int off = 32; off >= 1; off >>= 1)
        partial += __shfl_down(partial, off, 64);
    if (lane == 0) s_red[g] = partial;
    __syncthreads();
    if (tid == 0) out[n] = s_red[0] + s_red[1] + s_red[2] + s_red[3];
}

extern "C" void kernel_launch(void* const* d_in, const int* in_sizes, int n_in,
                              void* d_out, int out_size, void* d_ws, size_t ws_size,
                              hipStream_t stream) {
    const float* table     = (const float*)d_in[0];
    const float* w1        = (const float*)d_in[1];
    const float* w2        = (const float*)d_in[2];
    const int*   cand_idx  = (const int*)d_in[3];
    const int*   neigh_idx = (const int*)d_in[4];
    const int*   lengths   = (const int*)d_in[5];
    float* out = (float*)d_out;

    epanre_kernel<<<NROWS, 256, 0, stream>>>(table, w1, w2, cand_idx,
                                             neigh_idx, lengths, out);
}